// Round 1
// baseline (193.307 us; speedup 1.0000x reference)
//
#include <hip/hip_runtime.h>

// Problem constants: B=1, C=256, H=W=64 -> n=4096, HEADS=8, DIM_HEAD=64, inner=512
#define NSP   4096
#define CIN   256
#define INNER 512
#define QKV_ROWS 1536

// ---------------------------------------------------------------------------
// Generic fp32 tiled GEMM: C[M][N] = A[M][K] @ B[K][N], all row-major.
// BM=BN=64, BK=16, 256 threads (16x16), 4x4 micro-tile per thread.
// DO_BN=1: additionally accumulate per-output-row sum and sum-of-squares
// (for fused BatchNorm statistics) via wave-level reduce + atomics.
// ---------------------------------------------------------------------------
template<int DO_BN>
__global__ __launch_bounds__(256) void gemm_f32(
    const float* __restrict__ A, const float* __restrict__ B,
    float* __restrict__ C, int M, int N, int K,
    float* __restrict__ bn_sum, float* __restrict__ bn_sumsq)
{
    __shared__ float As[16][68];   // [k][m], padded: rows 16B-aligned, low conflict
    __shared__ float Bs[16][68];   // [k][n]
    const int tid = threadIdx.x;
    const int tx = tid & 15, ty = tid >> 4;
    const int row0 = blockIdx.y * 64;
    const int col0 = blockIdx.x * 64;

    float acc[4][4] = {};

    for (int k0 = 0; k0 < K; k0 += 16) {
        // A tile 64x16, one float4 along K per thread
        {
            const int r  = tid >> 2;          // 0..63
            const int kk = (tid & 3) * 4;     // 0,4,8,12
            const float4 a = *(const float4*)(A + (size_t)(row0 + r) * K + k0 + kk);
            As[kk + 0][r] = a.x; As[kk + 1][r] = a.y;
            As[kk + 2][r] = a.z; As[kk + 3][r] = a.w;
        }
        // B tile 16x64, one float4 along N per thread
        {
            const int kk = tid >> 4;          // 0..15
            const int n4 = (tid & 15) * 4;
            *(float4*)&Bs[kk][n4] = *(const float4*)(B + (size_t)(k0 + kk) * N + col0 + n4);
        }
        __syncthreads();
        #pragma unroll
        for (int kk = 0; kk < 16; ++kk) {
            const float4 a = *(const float4*)&As[kk][ty * 4];
            const float4 b = *(const float4*)&Bs[kk][tx * 4];
            const float av[4] = {a.x, a.y, a.z, a.w};
            const float bv[4] = {b.x, b.y, b.z, b.w};
            #pragma unroll
            for (int i = 0; i < 4; ++i)
                #pragma unroll
                for (int j = 0; j < 4; ++j)
                    acc[i][j] += av[i] * bv[j];
        }
        __syncthreads();
    }

    #pragma unroll
    for (int i = 0; i < 4; ++i) {
        float4 v = make_float4(acc[i][0], acc[i][1], acc[i][2], acc[i][3]);
        *(float4*)(C + (size_t)(row0 + ty * 4 + i) * N + col0 + tx * 4) = v;
    }

    if (DO_BN) {
        #pragma unroll
        for (int i = 0; i < 4; ++i) {
            float s = acc[i][0] + acc[i][1] + acc[i][2] + acc[i][3];
            float q = acc[i][0]*acc[i][0] + acc[i][1]*acc[i][1]
                    + acc[i][2]*acc[i][2] + acc[i][3]*acc[i][3];
            #pragma unroll
            for (int m = 1; m < 16; m <<= 1) {
                s += __shfl_xor(s, m, 64);
                q += __shfl_xor(q, m, 64);
            }
            if (tx == 0) {
                atomicAdd(bn_sum   + row0 + ty * 4 + i, s);
                atomicAdd(bn_sumsq + row0 + ty * 4 + i, q);
            }
        }
    }
}

// ---------------------------------------------------------------------------
// Per-(head, position) inverse norms: inv = rsqrt(sum_d q^2 + 1e-4)
// gid layout: [which(q=0,k=1)][g][n]; coalesced over n.
// ---------------------------------------------------------------------------
__global__ __launch_bounds__(256) void norms_kernel(
    const float* __restrict__ qkv,
    float* __restrict__ inv_qn, float* __restrict__ inv_kn)
{
    const int gid   = blockIdx.x * 256 + threadIdx.x;   // 0..65535
    const int which = gid >> 15;                        // 0=q, 1=k
    const int idx   = gid & 32767;                      // g*4096+n
    const int g = idx >> 12, n = idx & 4095;
    const float* base = qkv + (size_t)((which ? 512 : 0) + g * 64) * NSP + n;
    float s = 0.f;
    #pragma unroll 8
    for (int d = 0; d < 64; ++d) {
        const float v = base[(size_t)d * NSP];
        s += v * v;
    }
    const float r = rsqrtf(s + 1e-4f);
    (which ? inv_kn : inv_qn)[idx] = r;
}

// ---------------------------------------------------------------------------
// S[g][d1][d2] = sum_n (k[g,d1,n] * inv_kn[g,n]) * v[g,d2,n]
// Grid: (8 n-chunks of 512) x (8 heads). Partial sums -> atomicAdd.
// ---------------------------------------------------------------------------
__global__ __launch_bounds__(256) void s_kernel(
    const float* __restrict__ qkv, const float* __restrict__ inv_kn,
    float* __restrict__ S)
{
    const int g     = blockIdx.y;
    const int chunk = blockIdx.x;         // 8 chunks x 512 cols
    const int tid = threadIdx.x;
    const int tx = tid & 15, ty = tid >> 4;
    __shared__ float kt[64][65];
    __shared__ float vt[64][65];
    const float* kbase = qkv + (size_t)(512 + g * 64) * NSP;
    const float* vbase = qkv + (size_t)(1024 + g * 64) * NSP;
    const float* ikn   = inv_kn + g * NSP;

    float acc[4][4] = {};
    for (int t = 0; t < 8; ++t) {
        const int c0 = chunk * 512 + t * 64;
        for (int i = 0; i < 16; ++i) {
            const int idx = tid + i * 256;
            const int d = idx >> 6, nn = idx & 63;
            kt[d][nn] = kbase[(size_t)d * NSP + c0 + nn] * ikn[c0 + nn];
            vt[d][nn] = vbase[(size_t)d * NSP + c0 + nn];
        }
        __syncthreads();
        #pragma unroll
        for (int nn = 0; nn < 64; ++nn) {
            float a[4], b[4];
            #pragma unroll
            for (int i = 0; i < 4; ++i) a[i] = kt[ty * 4 + i][nn];
            #pragma unroll
            for (int j = 0; j < 4; ++j) b[j] = vt[tx * 4 + j][nn];
            #pragma unroll
            for (int i = 0; i < 4; ++i)
                #pragma unroll
                for (int j = 0; j < 4; ++j)
                    acc[i][j] += a[i] * b[j];
        }
        __syncthreads();
    }
    float* Sg = S + g * 4096;
    #pragma unroll
    for (int i = 0; i < 4; ++i)
        #pragma unroll
        for (int j = 0; j < 4; ++j)
            atomicAdd(Sg + (ty * 4 + i) * 64 + tx * 4 + j, acc[i][j]);
}

// ---------------------------------------------------------------------------
// attn_out[g*64+d2][n] = inv_qn[g,n] * sum_d1 q[g,d1,n] * S[g][d1][d2]
// Grid: (64 n-tiles of 64) x (8 heads). 256 threads = 64 cols x 4 d2-groups.
// ---------------------------------------------------------------------------
__global__ __launch_bounds__(256) void av_kernel(
    const float* __restrict__ qkv, const float* __restrict__ inv_qn,
    const float* __restrict__ S, float* __restrict__ attn_out)
{
    const int g  = blockIdx.y;
    const int n0 = blockIdx.x * 64;
    const int tid = threadIdx.x;
    const int nl = tid & 63;
    const int dg = tid >> 6;            // 0..3 -> d2 base dg*16
    __shared__ float Sl[64][64];
    __shared__ float qt[64][65];
    const float* qb  = qkv + (size_t)(g * 64) * NSP;
    const float* iqn = inv_qn + g * NSP;

    for (int i = 0; i < 16; ++i) {
        const int idx = tid + i * 256;
        const int d = idx >> 6, nn = idx & 63;
        Sl[d][nn] = S[g * 4096 + idx];
        qt[d][nn] = qb[(size_t)d * NSP + n0 + nn] * iqn[n0 + nn];
    }
    __syncthreads();

    float acc[16] = {};
    #pragma unroll 16
    for (int d1 = 0; d1 < 64; ++d1) {
        const float qv = qt[d1][nl];
        #pragma unroll
        for (int j = 0; j < 16; ++j) acc[j] += qv * Sl[d1][dg * 16 + j];
    }
    #pragma unroll
    for (int j = 0; j < 16; ++j)
        attn_out[(size_t)(g * 64 + dg * 16 + j) * NSP + n0 + nl] = acc[j];
}

// ---------------------------------------------------------------------------
// BN (training stats) + ReLU: out = relu((proj - mean) * rsqrt(var+eps) * gamma + beta)
// ---------------------------------------------------------------------------
__global__ __launch_bounds__(256) void bn_kernel(
    const float* __restrict__ proj,
    const float* __restrict__ bn_sum, const float* __restrict__ bn_sumsq,
    const float* __restrict__ gamma, const float* __restrict__ beta,
    float* __restrict__ out)
{
    const int gid = blockIdx.x * 256 + threadIdx.x;
    const int c = gid >> 12;
    const float mean = bn_sum[c] * (1.f / 4096.f);
    const float var  = bn_sumsq[c] * (1.f / 4096.f) - mean * mean;
    const float inv  = rsqrtf(var + 1e-5f);
    const float v = (proj[gid] - mean) * inv * gamma[c] + beta[c];
    out[gid] = v > 0.f ? v : 0.f;
}

// ---------------------------------------------------------------------------
extern "C" void kernel_launch(void* const* d_in, const int* in_sizes, int n_in,
                              void* d_out, int out_size, void* d_ws, size_t ws_size,
                              hipStream_t stream)
{
    const float* x      = (const float*)d_in[0];   // [256, 4096]
    const float* w_qkv  = (const float*)d_in[1];   // [1536, 256]
    const float* w_out  = (const float*)d_in[2];   // [256, 512]
    const float* gamma  = (const float*)d_in[3];   // [256]
    const float* beta   = (const float*)d_in[4];   // [256]
    float* out = (float*)d_out;                    // [256, 4096]

    float* ws      = (float*)d_ws;
    float* qkv     = ws;                           // 1536*4096 = 6291456
    float* inv_qn  = qkv     + 6291456;            // 8*4096 = 32768
    float* inv_kn  = inv_qn  + 32768;              // 32768
    float* S       = inv_kn  + 32768;              // 8*64*64 = 32768
    float* attn    = S       + 32768;              // 512*4096 = 2097152
    float* proj    = attn    + 2097152;            // 256*4096 = 1048576
    float* bn_sum  = proj    + 1048576;            // 256
    float* bn_sq   = bn_sum  + 256;                // 256

    // Accumulators must be zeroed every call (ws is re-poisoned to 0xAA).
    hipMemsetAsync(S, 0, 32768 * sizeof(float), stream);
    hipMemsetAsync(bn_sum, 0, 512 * sizeof(float), stream);

    // 1) qkv = w_qkv @ x : [1536,256] x [256,4096]
    gemm_f32<0><<<dim3(NSP / 64, QKV_ROWS / 64), 256, 0, stream>>>(
        w_qkv, x, qkv, QKV_ROWS, NSP, CIN, nullptr, nullptr);

    // 2) inverse q/k norms
    norms_kernel<<<256, 256, 0, stream>>>(qkv, inv_qn, inv_kn);

    // 3) S[g] = (K/kn) @ V^T per head (factored attention)
    s_kernel<<<dim3(8, 8), 256, 0, stream>>>(qkv, inv_kn, S);

    // 4) attn_out = (Q/qn) applied to S
    av_kernel<<<dim3(NSP / 64, 8), 256, 0, stream>>>(qkv, inv_qn, S, attn);

    // 5) proj = w_out @ attn_out, with fused BN statistics
    gemm_f32<1><<<dim3(NSP / 64, CIN / 64), 256, 0, stream>>>(
        w_out, attn, proj, CIN, NSP, INNER, bn_sum, bn_sq);

    // 6) BN + ReLU
    bn_kernel<<<CIN * NSP / 256, 256, 0, stream>>>(
        proj, bn_sum, bn_sq, gamma, beta, out);
}

// Round 4
// 146.894 us; speedup vs baseline: 1.3160x; 1.3160x over previous
//
#include <hip/hip_runtime.h>
#include <hip/hip_bf16.h>

// Problem constants: B=1, C=256, H=W=64 -> n=4096, HEADS=8, DIM_HEAD=64, inner=512
#define NSP   4096
#define CIN   256
#define INNER 512
#define QKV_ROWS 1536

typedef __attribute__((ext_vector_type(8))) short bf16x8;
typedef __attribute__((ext_vector_type(4))) float f32x4;

// ---------------------------------------------------------------------------
// fp32 -> bf16 elementwise convert (8 elems / thread, 16B stores)
// ---------------------------------------------------------------------------
__global__ __launch_bounds__(256) void convert_f2b(
    const float* __restrict__ src, __hip_bfloat16* __restrict__ dst, int n)
{
    const int i = (blockIdx.x * 256 + threadIdx.x) * 8;
    if (i >= n) return;
    const float4 a = *(const float4*)(src + i);
    const float4 b = *(const float4*)(src + i + 4);
    alignas(16) __hip_bfloat16 t[8];
    t[0] = __float2bfloat16(a.x); t[1] = __float2bfloat16(a.y);
    t[2] = __float2bfloat16(a.z); t[3] = __float2bfloat16(a.w);
    t[4] = __float2bfloat16(b.x); t[5] = __float2bfloat16(b.y);
    t[6] = __float2bfloat16(b.z); t[7] = __float2bfloat16(b.w);
    *(uint4*)(dst + i) = *(const uint4*)t;
}

// ---------------------------------------------------------------------------
// x [256][4096] fp32 -> xT [4096][256] bf16 (tiled transpose via LDS)
// ---------------------------------------------------------------------------
__global__ __launch_bounds__(256) void transpose_convert(
    const float* __restrict__ x, __hip_bfloat16* __restrict__ xT)
{
    __shared__ float t[64][65];
    const int n0 = blockIdx.x * 64, c0 = blockIdx.y * 64;
    const int tid = threadIdx.x;
    const int cl = tid >> 2, nl0 = (tid & 3) * 16;
    #pragma unroll
    for (int j = 0; j < 4; ++j) {
        const float4 v = *(const float4*)(x + (size_t)(c0 + cl) * NSP + n0 + nl0 + j * 4);
        t[cl][nl0 + j*4 + 0] = v.x; t[cl][nl0 + j*4 + 1] = v.y;
        t[cl][nl0 + j*4 + 2] = v.z; t[cl][nl0 + j*4 + 3] = v.w;
    }
    __syncthreads();
    const int nr = tid >> 2, cc0 = (tid & 3) * 16;
    alignas(16) __hip_bfloat16 tmp[16];
    #pragma unroll
    for (int j = 0; j < 16; ++j) tmp[j] = __float2bfloat16(t[cc0 + j][nr]);
    __hip_bfloat16* d = xT + (size_t)(n0 + nr) * CIN + c0 + cc0;   // FIX: + c0
    *(uint4*)(d)     = ((const uint4*)tmp)[0];
    *(uint4*)(d + 8) = ((const uint4*)tmp)[1];
}

// ---------------------------------------------------------------------------
// bf16 MFMA GEMM: C[M][N] = A[M][K] @ BT[N][K]^T   (A, BT row-major bf16)
// 128x128 tile, 4 waves (2x2), each wave 64x64 = 4x4 frags of 16x16x32.
// BK=64. global_load_lds width=16 with pre-swizzled source; XOR-swizzled
// ds_read_b128 (T2) to avoid the stride-128B 16-way bank conflict.
// ---------------------------------------------------------------------------
template<int K>
__global__ __launch_bounds__(256) void gemm_bf16(
    const __hip_bfloat16* __restrict__ A,
    const __hip_bfloat16* __restrict__ BT,
    __hip_bfloat16* __restrict__ C, int Nstride)
{
    __shared__ __hip_bfloat16 smem[2 * 128 * 64];
    __hip_bfloat16* As = smem;
    __hip_bfloat16* Bs = smem + 128 * 64;
    const int tid = threadIdx.x;
    const int w = tid >> 6, l = tid & 63;
    const int wr = w >> 1, wc = w & 1;
    const int row0 = blockIdx.y * 128, col0 = blockIdx.x * 128;

    f32x4 acc[4][4];
    #pragma unroll
    for (int i = 0; i < 4; ++i)
        #pragma unroll
        for (int j = 0; j < 4; ++j)
            acc[i][j] = (f32x4){0.f, 0.f, 0.f, 0.f};

    // Staging map: linear LDS dest byte o = i*4096 + w*1024 + l*16 holds the
    // element whose logical position is (row = o>>7, kbyte = (o&127) ^ ((row&7)<<4)).
    int srow[4], skel[4];
    #pragma unroll
    for (int i = 0; i < 4; ++i) {
        const int o = i * 4096 + w * 1024 + l * 16;
        srow[i] = o >> 7;
        skel[i] = ((o & 127) ^ ((srow[i] & 7) << 4)) >> 1;   // element offset in k
    }

    for (int kt = 0; kt < K; kt += 64) {
        #pragma unroll
        for (int i = 0; i < 4; ++i) {
            const __hip_bfloat16* ga = A + (size_t)(row0 + srow[i]) * K + kt + skel[i];
            __builtin_amdgcn_global_load_lds(
                (const __attribute__((address_space(1))) void*)ga,
                (__attribute__((address_space(3))) void*)((char*)As + i * 4096 + w * 1024),
                16, 0, 0);
        }
        #pragma unroll
        for (int i = 0; i < 4; ++i) {
            const __hip_bfloat16* gb = BT + (size_t)(col0 + srow[i]) * K + kt + skel[i];
            __builtin_amdgcn_global_load_lds(
                (const __attribute__((address_space(1))) void*)gb,
                (__attribute__((address_space(3))) void*)((char*)Bs + i * 4096 + w * 1024),
                16, 0, 0);
        }
        __syncthreads();   // compiler emits vmcnt(0) drain before s_barrier

        #pragma unroll
        for (int ks = 0; ks < 2; ++ks) {
            bf16x8 af[4], bfr[4];
            #pragma unroll
            for (int fr = 0; fr < 4; ++fr) {
                const int row = wr * 64 + fr * 16 + (l & 15);
                const int addr = row * 128 + ((ks * 64 + ((l >> 4) * 16)) ^ ((row & 7) << 4));
                af[fr] = *(const bf16x8*)((const char*)As + addr);
            }
            #pragma unroll
            for (int fc = 0; fc < 4; ++fc) {
                const int col = wc * 64 + fc * 16 + (l & 15);
                const int addr = col * 128 + ((ks * 64 + ((l >> 4) * 16)) ^ ((col & 7) << 4));
                bfr[fc] = *(const bf16x8*)((const char*)Bs + addr);
            }
            #pragma unroll
            for (int fr = 0; fr < 4; ++fr)
                #pragma unroll
                for (int fc = 0; fc < 4; ++fc)
                    acc[fr][fc] = __builtin_amdgcn_mfma_f32_16x16x32_bf16(
                        af[fr], bfr[fc], acc[fr][fc], 0, 0, 0);
        }
        __syncthreads();
    }

    // C/D layout (m89-verified): col = lane&15, row = (lane>>4)*4 + r
    #pragma unroll
    for (int fr = 0; fr < 4; ++fr)
        #pragma unroll
        for (int fc = 0; fc < 4; ++fc)
            #pragma unroll
            for (int r = 0; r < 4; ++r) {
                const int row = row0 + wr * 64 + fr * 16 + (l >> 4) * 4 + r;
                const int col = col0 + wc * 64 + fc * 16 + (l & 15);
                C[(size_t)row * Nstride + col] = __float2bfloat16(acc[fr][fc][r]);
            }
}

// ---------------------------------------------------------------------------
// inv-norms over d for q and k: rsqrt(sum_d v^2 + 1e-4)
// ---------------------------------------------------------------------------
__global__ __launch_bounds__(256) void norms_kernel(
    const __hip_bfloat16* __restrict__ qkv,
    float* __restrict__ inv_qn, float* __restrict__ inv_kn)
{
    const int gid   = blockIdx.x * 256 + threadIdx.x;   // 0..65535
    const int which = gid >> 15;                        // 0=q, 1=k
    const int idx   = gid & 32767;                      // g*4096+n
    const int g = idx >> 12, n = idx & 4095;
    const __hip_bfloat16* base = qkv + (size_t)((which ? 512 : 0) + g * 64) * NSP + n;
    float s = 0.f;
    #pragma unroll 8
    for (int d = 0; d < 64; ++d) {
        const float v = __bfloat162float(base[(size_t)d * NSP]);
        s += v * v;
    }
    (which ? inv_kn : inv_qn)[idx] = rsqrtf(s + 1e-4f);
}

// ---------------------------------------------------------------------------
// S[g][d1][d2] = sum_n k_hat[g,d1,n] * v[g,d2,n]  (factored attention)
// ---------------------------------------------------------------------------
__global__ __launch_bounds__(256) void s_kernel(
    const __hip_bfloat16* __restrict__ qkv, const float* __restrict__ inv_kn,
    float* __restrict__ S)
{
    const int g     = blockIdx.y;
    const int chunk = blockIdx.x;
    const int tid = threadIdx.x;
    const int tx = tid & 15, ty = tid >> 4;
    __shared__ float kt[64][65];
    __shared__ float vt[64][65];
    const __hip_bfloat16* kbase = qkv + (size_t)(512 + g * 64) * NSP;
    const __hip_bfloat16* vbase = qkv + (size_t)(1024 + g * 64) * NSP;
    const float* ikn = inv_kn + g * NSP;

    float acc[4][4] = {};
    for (int t = 0; t < 8; ++t) {
        const int c0 = chunk * 512 + t * 64;
        for (int i = 0; i < 16; ++i) {
            const int idx = tid + i * 256;
            const int d = idx >> 6, nn = idx & 63;
            kt[d][nn] = __bfloat162float(kbase[(size_t)d * NSP + c0 + nn]) * ikn[c0 + nn];
            vt[d][nn] = __bfloat162float(vbase[(size_t)d * NSP + c0 + nn]);
        }
        __syncthreads();
        #pragma unroll
        for (int nn = 0; nn < 64; ++nn) {
            float a[4], b[4];
            #pragma unroll
            for (int i = 0; i < 4; ++i) a[i] = kt[ty * 4 + i][nn];
            #pragma unroll
            for (int j = 0; j < 4; ++j) b[j] = vt[tx * 4 + j][nn];
            #pragma unroll
            for (int i = 0; i < 4; ++i)
                #pragma unroll
                for (int j = 0; j < 4; ++j)
                    acc[i][j] += a[i] * b[j];
        }
        __syncthreads();
    }
    float* Sg = S + g * 4096;
    #pragma unroll
    for (int i = 0; i < 4; ++i)
        #pragma unroll
        for (int j = 0; j < 4; ++j)
            atomicAdd(Sg + (ty * 4 + i) * 64 + tx * 4 + j, acc[i][j]);
}

// ---------------------------------------------------------------------------
// attnT[n][g*64+d2] = inv_qn[g,n] * sum_d1 q[g,d1,n] * S[g][d1][d2]   (bf16 out)
// ---------------------------------------------------------------------------
__global__ __launch_bounds__(256) void av_kernel(
    const __hip_bfloat16* __restrict__ qkv, const float* __restrict__ inv_qn,
    const float* __restrict__ S, __hip_bfloat16* __restrict__ attnT)
{
    const int g  = blockIdx.y;
    const int n0 = blockIdx.x * 64;
    const int tid = threadIdx.x;
    const int nl = tid & 63;
    const int dg = tid >> 6;            // 0..3 -> d2 base dg*16
    __shared__ float Sl[64][64];
    __shared__ float qt[64][65];
    const __hip_bfloat16* qb = qkv + (size_t)(g * 64) * NSP;
    const float* iqn = inv_qn + g * NSP;

    for (int i = 0; i < 16; ++i) {
        const int idx = tid + i * 256;
        const int d = idx >> 6, nn = idx & 63;
        Sl[d][nn] = S[g * 4096 + idx];
        qt[d][nn] = __bfloat162float(qb[(size_t)d * NSP + n0 + nn]) * iqn[n0 + nn];
    }
    __syncthreads();

    float acc[16] = {};
    #pragma unroll 16
    for (int d1 = 0; d1 < 64; ++d1) {
        const float qv = qt[d1][nl];
        #pragma unroll
        for (int j = 0; j < 16; ++j) acc[j] += qv * Sl[d1][dg * 16 + j];
    }
    alignas(16) __hip_bfloat16 tmp[16];
    #pragma unroll
    for (int j = 0; j < 16; ++j) tmp[j] = __float2bfloat16(acc[j]);
    __hip_bfloat16* d = attnT + (size_t)(n0 + nl) * INNER + g * 64 + dg * 16;
    *(uint4*)(d)     = ((const uint4*)tmp)[0];
    *(uint4*)(d + 8) = ((const uint4*)tmp)[1];
}

// ---------------------------------------------------------------------------
// Fused BN(training stats) + ReLU, one block per channel.
// ---------------------------------------------------------------------------
__global__ __launch_bounds__(256) void bn_fused(
    const __hip_bfloat16* __restrict__ proj,
    const float* __restrict__ gamma, const float* __restrict__ beta,
    float* __restrict__ out)
{
    const int c = blockIdx.x;
    const int tid = threadIdx.x;
    const __hip_bfloat16* p = proj + (size_t)c * NSP + tid * 16;
    float v[16];
    {
        const uint4 u0 = *(const uint4*)(p);
        const uint4 u1 = *(const uint4*)(p + 8);
        const __hip_bfloat16* b0 = (const __hip_bfloat16*)&u0;
        const __hip_bfloat16* b1 = (const __hip_bfloat16*)&u1;
        #pragma unroll
        for (int j = 0; j < 8; ++j) { v[j] = __bfloat162float(b0[j]); v[8 + j] = __bfloat162float(b1[j]); }
    }
    float s = 0.f, q = 0.f;
    #pragma unroll
    for (int j = 0; j < 16; ++j) { s += v[j]; q += v[j] * v[j]; }
    #pragma unroll
    for (int m = 1; m < 64; m <<= 1) { s += __shfl_xor(s, m, 64); q += __shfl_xor(q, m, 64); }
    __shared__ float ss[4], qq[4];
    if ((tid & 63) == 0) { ss[tid >> 6] = s; qq[tid >> 6] = q; }
    __syncthreads();
    s = ss[0] + ss[1] + ss[2] + ss[3];
    q = qq[0] + qq[1] + qq[2] + qq[3];
    const float mean = s * (1.f / 4096.f);
    const float var  = q * (1.f / 4096.f) - mean * mean;
    const float scal = rsqrtf(var + 1e-5f) * gamma[c];
    const float bb   = beta[c];
    float* o = out + (size_t)c * NSP + tid * 16;
    #pragma unroll
    for (int j = 0; j < 16; j += 4) {
        float4 r;
        r.x = (v[j+0] - mean) * scal + bb; r.x = r.x > 0.f ? r.x : 0.f;
        r.y = (v[j+1] - mean) * scal + bb; r.y = r.y > 0.f ? r.y : 0.f;
        r.z = (v[j+2] - mean) * scal + bb; r.z = r.z > 0.f ? r.z : 0.f;
        r.w = (v[j+3] - mean) * scal + bb; r.w = r.w > 0.f ? r.w : 0.f;
        *(float4*)(o + j) = r;
    }
}

// ---------------------------------------------------------------------------
extern "C" void kernel_launch(void* const* d_in, const int* in_sizes, int n_in,
                              void* d_out, int out_size, void* d_ws, size_t ws_size,
                              hipStream_t stream)
{
    const float* x      = (const float*)d_in[0];   // [256, 4096]
    const float* w_qkv  = (const float*)d_in[1];   // [1536, 256]
    const float* w_out  = (const float*)d_in[2];   // [256, 512]
    const float* gamma  = (const float*)d_in[3];   // [256]
    const float* beta   = (const float*)d_in[4];   // [256]
    float* out = (float*)d_out;                    // [256, 4096]

    char* ws = (char*)d_ws;
    __hip_bfloat16* qkv_bf  = (__hip_bfloat16*)ws;                    // 1536*4096*2 = 12.0 MB
    __hip_bfloat16* xT_bf   = (__hip_bfloat16*)(ws + 12582912);       // 4096*256*2  =  2.0 MB
    __hip_bfloat16* wqkv_bf = (__hip_bfloat16*)(ws + 14680064);       // 1536*256*2
    __hip_bfloat16* wout_bf = (__hip_bfloat16*)(ws + 15466496);       // 256*512*2
    __hip_bfloat16* attnT   = (__hip_bfloat16*)(ws + 15728640);       // 4096*512*2  =  4.0 MB
    __hip_bfloat16* proj_bf = (__hip_bfloat16*)(ws + 19922944);       // 256*4096*2  =  2.0 MB
    float* inv_qn = (float*)(ws + 22020096);                          // 32768 f
    float* inv_kn = inv_qn + 32768;
    float* S      = inv_kn + 32768;                                   // 8*64*64 f

    hipMemsetAsync(S, 0, 32768 * sizeof(float), stream);

    // weight / input conversion (bf16)
    convert_f2b<<<QKV_ROWS * CIN / (8 * 256), 256, 0, stream>>>(w_qkv, wqkv_bf, QKV_ROWS * CIN);
    convert_f2b<<<CIN * INNER / (8 * 256), 256, 0, stream>>>(w_out, wout_bf, CIN * INNER);
    transpose_convert<<<dim3(NSP / 64, CIN / 64), 256, 0, stream>>>(x, xT_bf);

    // 1) qkv = w_qkv @ x  (MFMA, bf16): [1536,256] x [256,4096]
    gemm_bf16<CIN><<<dim3(NSP / 128, QKV_ROWS / 128), 256, 0, stream>>>(
        wqkv_bf, xT_bf, qkv_bf, NSP);

    // 2) inverse q/k norms
    norms_kernel<<<256, 256, 0, stream>>>(qkv_bf, inv_qn, inv_kn);

    // 3) S[g] = K_hat @ V^T per head
    s_kernel<<<dim3(8, 8), 256, 0, stream>>>(qkv_bf, inv_kn, S);

    // 4) attnT = (Q_hat^T S)^T, bf16 [4096][512]
    av_kernel<<<dim3(NSP / 64, 8), 256, 0, stream>>>(qkv_bf, inv_qn, S, attnT);

    // 5) proj = w_out @ attn (MFMA, bf16): [256,512] x [512,4096]
    gemm_bf16<INNER><<<dim3(NSP / 128, CIN / 128), 256, 0, stream>>>(
        wout_bf, attnT, proj_bf, NSP);

    // 6) BN stats + normalize + ReLU (fused, per-channel)
    bn_fused<<<CIN, 256, 0, stream>>>(proj_bf, gamma, beta, out);
}

// Round 9
// 105.509 us; speedup vs baseline: 1.8321x; 1.3922x over previous
//
#include <hip/hip_runtime.h>
#include <hip/hip_bf16.h>

// Problem constants: B=1, C=256, H=W=64 -> n=4096, HEADS=8, DIM_HEAD=64, inner=512
#define NSP   4096
#define CIN   256
#define INNER 512
#define QKV_ROWS 1536

typedef __attribute__((ext_vector_type(8))) short bf16x8;
typedef __attribute__((ext_vector_type(4))) float f32x4;

// ---------------------------------------------------------------------------
// Both weight tensors fp32 -> bf16 in one launch.
// ---------------------------------------------------------------------------
__global__ __launch_bounds__(256) void conv_weights(
    const float* __restrict__ w_qkv, const float* __restrict__ w_out,
    __hip_bfloat16* __restrict__ dq, __hip_bfloat16* __restrict__ do_)
{
    const int gid = blockIdx.x * 256 + threadIdx.x;
    const int i = gid * 8;
    const float* src;
    __hip_bfloat16* dst;
    int off;
    if (i < QKV_ROWS * CIN) { src = w_qkv; dst = dq;  off = i; }
    else                    { src = w_out; dst = do_; off = i - QKV_ROWS * CIN; }
    const float4 a = *(const float4*)(src + off);
    const float4 b = *(const float4*)(src + off + 4);
    alignas(16) __hip_bfloat16 t[8];
    t[0] = __float2bfloat16(a.x); t[1] = __float2bfloat16(a.y);
    t[2] = __float2bfloat16(a.z); t[3] = __float2bfloat16(a.w);
    t[4] = __float2bfloat16(b.x); t[5] = __float2bfloat16(b.y);
    t[6] = __float2bfloat16(b.z); t[7] = __float2bfloat16(b.w);
    *(uint4*)(dst + off) = *(const uint4*)t;
}

// ---------------------------------------------------------------------------
// x [256][4096] fp32 -> xT [4096][256] bf16 (tiled transpose via LDS)
// ---------------------------------------------------------------------------
__global__ __launch_bounds__(256) void transpose_convert(
    const float* __restrict__ x, __hip_bfloat16* __restrict__ xT)
{
    __shared__ float t[64][65];
    const int n0 = blockIdx.x * 64, c0 = blockIdx.y * 64;
    const int tid = threadIdx.x;
    const int cl = tid >> 2, nl0 = (tid & 3) * 16;
    #pragma unroll
    for (int j = 0; j < 4; ++j) {
        const float4 v = *(const float4*)(x + (size_t)(c0 + cl) * NSP + n0 + nl0 + j * 4);
        t[cl][nl0 + j*4 + 0] = v.x; t[cl][nl0 + j*4 + 1] = v.y;
        t[cl][nl0 + j*4 + 2] = v.z; t[cl][nl0 + j*4 + 3] = v.w;
    }
    __syncthreads();
    const int nr = tid >> 2, cc0 = (tid & 3) * 16;
    alignas(16) __hip_bfloat16 tmp[16];
    #pragma unroll
    for (int j = 0; j < 16; ++j) tmp[j] = __float2bfloat16(t[cc0 + j][nr]);
    __hip_bfloat16* d = xT + (size_t)(n0 + nr) * CIN + c0 + cc0;
    *(uint4*)(d)     = ((const uint4*)tmp)[0];
    *(uint4*)(d + 8) = ((const uint4*)tmp)[1];
}

// ---------------------------------------------------------------------------
// bf16 MFMA GEMM: C[M][N] = A[M][K] @ BT[N][K]^T.
// BM x 128 tile, 4 waves (2x2), wave tile (FR*16) x 64, frags of 16x16x32.
// global_load_lds width=16 with pre-swizzled source + XOR-swizzled ds_read.
// DO_NORMS (qkv only, BM=128): fused q/k inverse norms (one wave = one head)
// and a register-sourced transposed side-write of the q rows into qT[n][512].
// ---------------------------------------------------------------------------
template<int K, int BM, int FR, int DO_NORMS>
__global__ __launch_bounds__(256) void gemm_bf16(
    const __hip_bfloat16* __restrict__ A,
    const __hip_bfloat16* __restrict__ BT,
    __hip_bfloat16* __restrict__ C, int Nstride,
    float* __restrict__ inv_qn, float* __restrict__ inv_kn,
    __hip_bfloat16* __restrict__ qT)
{
    __shared__ __hip_bfloat16 smem[(BM + 128) * 64];
    __hip_bfloat16* As = smem;
    __hip_bfloat16* Bs = smem + BM * 64;
    const int tid = threadIdx.x;
    const int w = tid >> 6, l = tid & 63;
    const int wr = w >> 1, wc = w & 1;
    const int row0 = blockIdx.y * BM, col0 = blockIdx.x * 128;

    f32x4 acc[FR][4];
    #pragma unroll
    for (int i = 0; i < FR; ++i)
        #pragma unroll
        for (int j = 0; j < 4; ++j)
            acc[i][j] = (f32x4){0.f, 0.f, 0.f, 0.f};

    for (int kt = 0; kt < K; kt += 64) {
        #pragma unroll
        for (int i = 0; i < BM / 32; ++i) {
            const int o = i * 4096 + w * 1024 + l * 16;
            const int r_ = o >> 7;
            const int kel = ((o & 127) ^ ((r_ & 7) << 4)) >> 1;
            __builtin_amdgcn_global_load_lds(
                (const __attribute__((address_space(1))) void*)(A + (size_t)(row0 + r_) * K + kt + kel),
                (__attribute__((address_space(3))) void*)((char*)As + o),
                16, 0, 0);
        }
        #pragma unroll
        for (int i = 0; i < 4; ++i) {
            const int o = i * 4096 + w * 1024 + l * 16;
            const int r_ = o >> 7;
            const int kel = ((o & 127) ^ ((r_ & 7) << 4)) >> 1;
            __builtin_amdgcn_global_load_lds(
                (const __attribute__((address_space(1))) void*)(BT + (size_t)(col0 + r_) * K + kt + kel),
                (__attribute__((address_space(3))) void*)((char*)Bs + o),
                16, 0, 0);
        }
        __syncthreads();

        #pragma unroll
        for (int ks = 0; ks < 2; ++ks) {
            bf16x8 af[FR], bfr[4];
            #pragma unroll
            for (int fr = 0; fr < FR; ++fr) {
                const int row = wr * FR * 16 + fr * 16 + (l & 15);
                const int addr = row * 128 + ((ks * 64 + ((l >> 4) * 16)) ^ ((row & 7) << 4));
                af[fr] = *(const bf16x8*)((const char*)As + addr);
            }
            #pragma unroll
            for (int fc = 0; fc < 4; ++fc) {
                const int col = wc * 64 + fc * 16 + (l & 15);
                const int addr = col * 128 + ((ks * 64 + ((l >> 4) * 16)) ^ ((col & 7) << 4));
                bfr[fc] = *(const bf16x8*)((const char*)Bs + addr);
            }
            #pragma unroll
            for (int fr = 0; fr < FR; ++fr)
                #pragma unroll
                for (int fc = 0; fc < 4; ++fc)
                    acc[fr][fc] = __builtin_amdgcn_mfma_f32_16x16x32_bf16(
                        af[fr], bfr[fc], acc[fr][fc], 0, 0, 0);
        }
        __syncthreads();
    }

    // C/D layout (m89-verified): col = lane&15, row = (lane>>4)*4 + r
    #pragma unroll
    for (int fr = 0; fr < FR; ++fr)
        #pragma unroll
        for (int fc = 0; fc < 4; ++fc)
            #pragma unroll
            for (int r = 0; r < 4; ++r) {
                const int row = row0 + wr * FR * 16 + fr * 16 + (l >> 4) * 4 + r;
                const int col = col0 + wc * 64 + fc * 16 + (l & 15);
                C[(size_t)row * Nstride + col] = __float2bfloat16(acc[fr][fc][r]);
            }

    if constexpr (DO_NORMS) {
        const int chbase = row0 + wr * 64;   // wave's 64 rows = one head
        if (chbase < 1024) {                 // q or k rows
            const int head = chbase >> 6;    // 0..7 = q, 8..15 = k
            #pragma unroll
            for (int fc = 0; fc < 4; ++fc) {
                float s = 0.f;
                #pragma unroll
                for (int fr = 0; fr < FR; ++fr)
                    #pragma unroll
                    for (int r = 0; r < 4; ++r)
                        s += acc[fr][fc][r] * acc[fr][fc][r];
                s += __shfl_xor(s, 16, 64);
                s += __shfl_xor(s, 32, 64);
                if ((l >> 4) == 0) {
                    const int col = col0 + wc * 64 + fc * 16 + l;
                    const float inv = rsqrtf(s + 1e-4f);
                    if (head < 8) inv_qn[head * NSP + col] = inv;
                    else          inv_kn[(head - 8) * NSP + col] = inv;
                }
            }
        }
        if (chbase < 512) {                  // q rows: transposed side-write
            #pragma unroll
            for (int fr = 0; fr < FR; ++fr)
                #pragma unroll
                for (int fc = 0; fc < 4; ++fc) {
                    const int rowb = chbase + fr * 16 + (l >> 4) * 4;
                    const int col  = col0 + wc * 64 + fc * 16 + (l & 15);
                    alignas(8) __hip_bfloat16 t4[4];
                    #pragma unroll
                    for (int r = 0; r < 4; ++r) t4[r] = __float2bfloat16(acc[fr][fc][r]);
                    *(unsigned long long*)(qT + (size_t)col * INNER + rowb) =
                        *(const unsigned long long*)t4;
                }
        }
    }
}

// ---------------------------------------------------------------------------
__device__ inline bf16x8 scale8(bf16x8 a, float4 s0, float4 s1) {
    union { bf16x8 v; unsigned short u[8]; } in, out;
    in.v = a;
    const float s[8] = {s0.x, s0.y, s0.z, s0.w, s1.x, s1.y, s1.z, s1.w};
    #pragma unroll
    for (int j = 0; j < 8; ++j) {
        const float f = __uint_as_float(((unsigned)(unsigned short)in.u[j]) << 16) * s[j];
        const __hip_bfloat16 h = __float2bfloat16(f);
        out.u[j] = *(const unsigned short*)&h;
    }
    return out.v;
}

// ---------------------------------------------------------------------------
// S partials via MFMA, operands direct from global (L2-resident).
// S_part[c][g][d1][d2] = sum_{n in chunk c} k_hat[g,d1,n] * v[g,d2,n]
// grid (32 chunks of 128 n, 8 heads); 4 waves, wave = 16 d1 rows.
// ---------------------------------------------------------------------------
__global__ __launch_bounds__(256) void s_mfma(
    const __hip_bfloat16* __restrict__ qkv, const float* __restrict__ inv_kn,
    float* __restrict__ S_part)
{
    const int c = blockIdx.x, g = blockIdx.y;
    const int tid = threadIdx.x;
    const int w = tid >> 6, l = tid & 63;
    const __hip_bfloat16* kb = qkv + (size_t)(512 + g * 64 + w * 16 + (l & 15)) * NSP;
    const float* ikn = inv_kn + g * NSP;

    f32x4 acc[4];
    #pragma unroll
    for (int j = 0; j < 4; ++j) acc[j] = (f32x4){0.f, 0.f, 0.f, 0.f};

    #pragma unroll
    for (int s8 = 0; s8 < 4; ++s8) {
        const int na = c * 128 + s8 * 32 + (l >> 4) * 8;
        bf16x8 a = *(const bf16x8*)(kb + na);
        const float4 i0 = *(const float4*)(ikn + na);
        const float4 i1 = *(const float4*)(ikn + na + 4);
        a = scale8(a, i0, i1);
        #pragma unroll
        for (int fc = 0; fc < 4; ++fc) {
            const bf16x8 b = *(const bf16x8*)(
                qkv + (size_t)(1024 + g * 64 + fc * 16 + (l & 15)) * NSP + na);
            acc[fc] = __builtin_amdgcn_mfma_f32_16x16x32_bf16(a, b, acc[fc], 0, 0, 0);
        }
    }
    float* out = S_part + (size_t)(c * 8 + g) * 4096;
    #pragma unroll
    for (int fc = 0; fc < 4; ++fc)
        #pragma unroll
        for (int r = 0; r < 4; ++r)
            out[(w * 16 + (l >> 4) * 4 + r) * 64 + fc * 16 + (l & 15)] = acc[fc][r];
}

// ---------------------------------------------------------------------------
// Reduce 32 partials; emit SbT[g][d2][d1] bf16 (B-operand layout for av).
// ---------------------------------------------------------------------------
__global__ __launch_bounds__(256) void s_reduce(
    const float* __restrict__ S_part, __hip_bfloat16* __restrict__ SbT)
{
    const int t = blockIdx.x * 256 + threadIdx.x;      // 32768
    const int g = t >> 12, rem = t & 4095;
    const int d1 = rem >> 6, d2 = rem & 63;
    float s = 0.f;
    #pragma unroll
    for (int c = 0; c < 32; ++c)
        s += S_part[(size_t)(c * 8 + g) * 4096 + d1 * 64 + d2];
    SbT[g * 4096 + d2 * 64 + d1] = __float2bfloat16(s);
}

// ---------------------------------------------------------------------------
// attnT[n][g*64+d2] = iqn[g,n] * sum_d1 qT[n][g*64+d1] * S[g][d1][d2] (MFMA).
// S fragments register-resident; iqn applied to f32 acc at epilogue.
// grid (16 n-tiles of 256, 8 heads); 4 waves, wave = 64 n rows.
// ---------------------------------------------------------------------------
__global__ __launch_bounds__(256) void av_mfma(
    const __hip_bfloat16* __restrict__ qT, const float* __restrict__ inv_qn,
    const __hip_bfloat16* __restrict__ SbT, __hip_bfloat16* __restrict__ attnT)
{
    const int nb = blockIdx.x, g = blockIdx.y;
    const int tid = threadIdx.x;
    const int w = tid >> 6, l = tid & 63;
    const int nwave = nb * 256 + w * 64;

    bf16x8 bfr[2][4];
    #pragma unroll
    for (int ks = 0; ks < 2; ++ks)
        #pragma unroll
        for (int fc = 0; fc < 4; ++fc)
            bfr[ks][fc] = *(const bf16x8*)(
                SbT + g * 4096 + (fc * 16 + (l & 15)) * 64 + ks * 32 + (l >> 4) * 8);

    #pragma unroll
    for (int mr = 0; mr < 4; ++mr) {
        f32x4 acc[4];
        #pragma unroll
        for (int j = 0; j < 4; ++j) acc[j] = (f32x4){0.f, 0.f, 0.f, 0.f};
        #pragma unroll
        for (int ks = 0; ks < 2; ++ks) {
            const bf16x8 a = *(const bf16x8*)(
                qT + (size_t)(nwave + mr * 16 + (l & 15)) * INNER + g * 64 + ks * 32 + (l >> 4) * 8);
            #pragma unroll
            for (int fc = 0; fc < 4; ++fc)
                acc[fc] = __builtin_amdgcn_mfma_f32_16x16x32_bf16(a, bfr[ks][fc], acc[fc], 0, 0, 0);
        }
        const int nrow = nwave + mr * 16 + (l >> 4) * 4;
        const float4 iq = *(const float4*)(inv_qn + g * NSP + nrow);
        const float iqa[4] = {iq.x, iq.y, iq.z, iq.w};
        #pragma unroll
        for (int fc = 0; fc < 4; ++fc)
            #pragma unroll
            for (int r = 0; r < 4; ++r)
                attnT[(size_t)(nrow + r) * INNER + g * 64 + fc * 16 + (l & 15)] =
                    __float2bfloat16(acc[fc][r] * iqa[r]);
    }
}

// ---------------------------------------------------------------------------
// Fused BN(training stats) + ReLU, one block per channel.
// ---------------------------------------------------------------------------
__global__ __launch_bounds__(256) void bn_fused(
    const __hip_bfloat16* __restrict__ proj,
    const float* __restrict__ gamma, const float* __restrict__ beta,
    float* __restrict__ out)
{
    const int c = blockIdx.x;
    const int tid = threadIdx.x;
    const __hip_bfloat16* p = proj + (size_t)c * NSP + tid * 16;
    float v[16];
    {
        const uint4 u0 = *(const uint4*)(p);
        const uint4 u1 = *(const uint4*)(p + 8);
        const __hip_bfloat16* b0 = (const __hip_bfloat16*)&u0;
        const __hip_bfloat16* b1 = (const __hip_bfloat16*)&u1;
        #pragma unroll
        for (int j = 0; j < 8; ++j) { v[j] = __bfloat162float(b0[j]); v[8 + j] = __bfloat162float(b1[j]); }
    }
    float s = 0.f, q = 0.f;
    #pragma unroll
    for (int j = 0; j < 16; ++j) { s += v[j]; q += v[j] * v[j]; }
    #pragma unroll
    for (int m = 1; m < 64; m <<= 1) { s += __shfl_xor(s, m, 64); q += __shfl_xor(q, m, 64); }
    __shared__ float ss[4], qq[4];
    if ((tid & 63) == 0) { ss[tid >> 6] = s; qq[tid >> 6] = q; }
    __syncthreads();
    s = ss[0] + ss[1] + ss[2] + ss[3];
    q = qq[0] + qq[1] + qq[2] + qq[3];
    const float mean = s * (1.f / 4096.f);
    const float var  = q * (1.f / 4096.f) - mean * mean;
    const float scal = rsqrtf(var + 1e-5f) * gamma[c];
    const float bb   = beta[c];
    float* o = out + (size_t)c * NSP + tid * 16;
    #pragma unroll
    for (int j = 0; j < 16; j += 4) {
        float4 r;
        r.x = (v[j+0] - mean) * scal + bb; r.x = r.x > 0.f ? r.x : 0.f;
        r.y = (v[j+1] - mean) * scal + bb; r.y = r.y > 0.f ? r.y : 0.f;
        r.z = (v[j+2] - mean) * scal + bb; r.z = r.z > 0.f ? r.z : 0.f;
        r.w = (v[j+3] - mean) * scal + bb; r.w = r.w > 0.f ? r.w : 0.f;
        *(float4*)(o + j) = r;
    }
}

// ---------------------------------------------------------------------------
extern "C" void kernel_launch(void* const* d_in, const int* in_sizes, int n_in,
                              void* d_out, int out_size, void* d_ws, size_t ws_size,
                              hipStream_t stream)
{
    const float* x      = (const float*)d_in[0];   // [256, 4096]
    const float* w_qkv  = (const float*)d_in[1];   // [1536, 256]
    const float* w_out  = (const float*)d_in[2];   // [256, 512]
    const float* gamma  = (const float*)d_in[3];   // [256]
    const float* beta   = (const float*)d_in[4];   // [256]
    float* out = (float*)d_out;                    // [256, 4096]

    char* ws = (char*)d_ws;
    __hip_bfloat16* qkv_bf  = (__hip_bfloat16*)ws;                    // 12 MB
    __hip_bfloat16* xT_bf   = (__hip_bfloat16*)(ws + 12582912);       // 2 MB
    __hip_bfloat16* wqkv_bf = (__hip_bfloat16*)(ws + 14680064);       // 768 KB
    __hip_bfloat16* wout_bf = (__hip_bfloat16*)(ws + 15466496);       // 256 KB
    __hip_bfloat16* attnT   = (__hip_bfloat16*)(ws + 15728640);       // 4 MB
    __hip_bfloat16* proj_bf = (__hip_bfloat16*)(ws + 19922944);       // 2 MB
    float* inv_qn           = (float*)(ws + 22020096);                // 128 KB
    float* inv_kn           = (float*)(ws + 22151168);                // 128 KB
    __hip_bfloat16* qT      = (__hip_bfloat16*)(ws + 22282240);       // 4 MB
    float* S_part           = (float*)(ws + 26476544);                // 4 MB
    __hip_bfloat16* SbT     = (__hip_bfloat16*)(ws + 30670848);       // 64 KB

    // weight / input conversion (bf16)
    conv_weights<<<(QKV_ROWS * CIN + CIN * INNER) / 2048, 256, 0, stream>>>(
        w_qkv, w_out, wqkv_bf, wout_bf);
    transpose_convert<<<dim3(NSP / 64, CIN / 64), 256, 0, stream>>>(x, xT_bf);

    // 1) qkv = w_qkv @ x (MFMA) + fused inv-norms + qT side-write
    gemm_bf16<CIN, 128, 4, 1><<<dim3(NSP / 128, QKV_ROWS / 128), 256, 0, stream>>>(
        wqkv_bf, xT_bf, qkv_bf, NSP, inv_qn, inv_kn, qT);

    // 2) S partials = K_hat @ V^T per head (MFMA, direct-from-global)
    s_mfma<<<dim3(32, 8), 256, 0, stream>>>(qkv_bf, inv_kn, S_part);

    // 3) reduce partials -> SbT bf16 [g][d2][d1]
    s_reduce<<<128, 256, 0, stream>>>(S_part, SbT);

    // 4) attnT = iqn * (qT @ S) (MFMA, S in registers)
    av_mfma<<<dim3(16, 8), 256, 0, stream>>>(qT, inv_qn, SbT, attnT);

    // 5) proj = w_out @ attn (MFMA, BM=64 -> 128 blocks)
    gemm_bf16<INNER, 64, 2, 0><<<dim3(NSP / 128, CIN / 64), 256, 0, stream>>>(
        wout_bf, attnT, proj_bf, NSP, nullptr, nullptr, nullptr);

    // 6) BN stats + normalize + ReLU (fused, per-channel)
    bn_fused<<<CIN, 256, 0, stream>>>(proj_bf, gamma, beta, out);
}

// Round 10
// 104.270 us; speedup vs baseline: 1.8539x; 1.0119x over previous
//
#include <hip/hip_runtime.h>
#include <hip/hip_bf16.h>

// Problem constants: B=1, C=256, H=W=64 -> n=4096, HEADS=8, DIM_HEAD=64, inner=512
#define NSP   4096
#define CIN   256
#define INNER 512
#define QKV_ROWS 1536

typedef __attribute__((ext_vector_type(8))) short bf16x8;
typedef __attribute__((ext_vector_type(4))) float f32x4;

// ---------------------------------------------------------------------------
// Merged prep: x transpose+convert (blocks 0..255) and both weight converts
// (blocks 256..511). One launch instead of two.
// ---------------------------------------------------------------------------
__global__ __launch_bounds__(256) void prep(
    const float* __restrict__ x, const float* __restrict__ w_qkv,
    const float* __restrict__ w_out,
    __hip_bfloat16* __restrict__ xT, __hip_bfloat16* __restrict__ wq,
    __hip_bfloat16* __restrict__ wo)
{
    __shared__ float t[64][65];
    const int bx = blockIdx.x;
    const int tid = threadIdx.x;
    if (bx < 256) {
        // x [256][4096] fp32 -> xT [4096][256] bf16
        const int n0 = (bx & 63) * 64, c0 = (bx >> 6) * 64;
        const int cl = tid >> 2, nl0 = (tid & 3) * 16;
        #pragma unroll
        for (int j = 0; j < 4; ++j) {
            const float4 v = *(const float4*)(x + (size_t)(c0 + cl) * NSP + n0 + nl0 + j * 4);
            t[cl][nl0 + j*4 + 0] = v.x; t[cl][nl0 + j*4 + 1] = v.y;
            t[cl][nl0 + j*4 + 2] = v.z; t[cl][nl0 + j*4 + 3] = v.w;
        }
        __syncthreads();
        const int nr = tid >> 2, cc0 = (tid & 3) * 16;
        alignas(16) __hip_bfloat16 tmp[16];
        #pragma unroll
        for (int j = 0; j < 16; ++j) tmp[j] = __float2bfloat16(t[cc0 + j][nr]);
        __hip_bfloat16* d = xT + (size_t)(n0 + nr) * CIN + c0 + cc0;
        *(uint4*)(d)     = ((const uint4*)tmp)[0];
        *(uint4*)(d + 8) = ((const uint4*)tmp)[1];
    } else {
        const int i = ((bx - 256) * 256 + tid) * 8;
        const float* src;
        __hip_bfloat16* dst;
        int off;
        if (i < QKV_ROWS * CIN) { src = w_qkv; dst = wq; off = i; }
        else                    { src = w_out; dst = wo; off = i - QKV_ROWS * CIN; }
        const float4 a = *(const float4*)(src + off);
        const float4 b = *(const float4*)(src + off + 4);
        alignas(16) __hip_bfloat16 tt[8];
        tt[0] = __float2bfloat16(a.x); tt[1] = __float2bfloat16(a.y);
        tt[2] = __float2bfloat16(a.z); tt[3] = __float2bfloat16(a.w);
        tt[4] = __float2bfloat16(b.x); tt[5] = __float2bfloat16(b.y);
        tt[6] = __float2bfloat16(b.z); tt[7] = __float2bfloat16(b.w);
        *(uint4*)(dst + off) = *(const uint4*)tt;
    }
}

// ---------------------------------------------------------------------------
// bf16 MFMA GEMM: C[M][N] = A[M][K] @ BT[N][K]^T.
// BM x 128 tile, 4 waves (2x2), wave tile (FR*16) x 64, frags of 16x16x32.
// global_load_lds width=16 with pre-swizzled source + XOR-swizzled ds_read.
// DO_NORMS (qkv only, BM=128): per-wave head norms via butterfly (valid in
// ALL lanes), then k-hat = k*inv written to C, q-hat = q*inv written
// (transposed) to qT. q rows are NOT written to C (nothing reads them).
// ---------------------------------------------------------------------------
template<int K, int BM, int FR, int DO_NORMS>
__global__ __launch_bounds__(256) void gemm_bf16(
    const __hip_bfloat16* __restrict__ A,
    const __hip_bfloat16* __restrict__ BT,
    __hip_bfloat16* __restrict__ C, int Nstride,
    __hip_bfloat16* __restrict__ qT)
{
    __shared__ __hip_bfloat16 smem[(BM + 128) * 64];
    __hip_bfloat16* As = smem;
    __hip_bfloat16* Bs = smem + BM * 64;
    const int tid = threadIdx.x;
    const int w = tid >> 6, l = tid & 63;
    const int wr = w >> 1, wc = w & 1;
    const int row0 = blockIdx.y * BM, col0 = blockIdx.x * 128;

    f32x4 acc[FR][4];
    #pragma unroll
    for (int i = 0; i < FR; ++i)
        #pragma unroll
        for (int j = 0; j < 4; ++j)
            acc[i][j] = (f32x4){0.f, 0.f, 0.f, 0.f};

    for (int kt = 0; kt < K; kt += 64) {
        #pragma unroll
        for (int i = 0; i < BM / 32; ++i) {
            const int o = i * 4096 + w * 1024 + l * 16;
            const int r_ = o >> 7;
            const int kel = ((o & 127) ^ ((r_ & 7) << 4)) >> 1;
            __builtin_amdgcn_global_load_lds(
                (const __attribute__((address_space(1))) void*)(A + (size_t)(row0 + r_) * K + kt + kel),
                (__attribute__((address_space(3))) void*)((char*)As + o),
                16, 0, 0);
        }
        #pragma unroll
        for (int i = 0; i < 4; ++i) {
            const int o = i * 4096 + w * 1024 + l * 16;
            const int r_ = o >> 7;
            const int kel = ((o & 127) ^ ((r_ & 7) << 4)) >> 1;
            __builtin_amdgcn_global_load_lds(
                (const __attribute__((address_space(1))) void*)(BT + (size_t)(col0 + r_) * K + kt + kel),
                (__attribute__((address_space(3))) void*)((char*)Bs + o),
                16, 0, 0);
        }
        __syncthreads();

        #pragma unroll
        for (int ks = 0; ks < 2; ++ks) {
            bf16x8 af[FR], bfr[4];
            #pragma unroll
            for (int fr = 0; fr < FR; ++fr) {
                const int row = wr * FR * 16 + fr * 16 + (l & 15);
                const int addr = row * 128 + ((ks * 64 + ((l >> 4) * 16)) ^ ((row & 7) << 4));
                af[fr] = *(const bf16x8*)((const char*)As + addr);
            }
            #pragma unroll
            for (int fc = 0; fc < 4; ++fc) {
                const int col = wc * 64 + fc * 16 + (l & 15);
                const int addr = col * 128 + ((ks * 64 + ((l >> 4) * 16)) ^ ((col & 7) << 4));
                bfr[fc] = *(const bf16x8*)((const char*)Bs + addr);
            }
            #pragma unroll
            for (int fr = 0; fr < FR; ++fr)
                #pragma unroll
                for (int fc = 0; fc < 4; ++fc)
                    acc[fr][fc] = __builtin_amdgcn_mfma_f32_16x16x32_bf16(
                        af[fr], bfr[fc], acc[fr][fc], 0, 0, 0);
        }
        __syncthreads();
    }

    // C/D layout (m89-verified): col = lane&15, row = (lane>>4)*4 + r
    if constexpr (DO_NORMS) {
        const int chbase = row0 + wr * 64;   // wave's 64 rows = one head slice
        float inv[4] = {1.f, 1.f, 1.f, 1.f};
        if (chbase < 1024) {                 // q or k: per-column inverse norm
            #pragma unroll
            for (int fc = 0; fc < 4; ++fc) {
                float s = 0.f;
                #pragma unroll
                for (int fr = 0; fr < FR; ++fr)
                    #pragma unroll
                    for (int r = 0; r < 4; ++r)
                        s += acc[fr][fc][r] * acc[fr][fc][r];
                s += __shfl_xor(s, 16, 64);   // butterfly: sum valid in all lanes
                s += __shfl_xor(s, 32, 64);
                inv[fc] = rsqrtf(s + 1e-4f);
            }
        }
        if (chbase < 512) {
            // q-hat: transposed side-write only (C row never read)
            #pragma unroll
            for (int fr = 0; fr < FR; ++fr)
                #pragma unroll
                for (int fc = 0; fc < 4; ++fc) {
                    const int rowb = chbase + fr * 16 + (l >> 4) * 4;
                    const int col  = col0 + wc * 64 + fc * 16 + (l & 15);
                    alignas(8) __hip_bfloat16 t4[4];
                    #pragma unroll
                    for (int r = 0; r < 4; ++r)
                        t4[r] = __float2bfloat16(acc[fr][fc][r] * inv[fc]);
                    *(unsigned long long*)(qT + (size_t)col * INNER + rowb) =
                        *(const unsigned long long*)t4;
                }
        } else {
            // k-hat (scaled) or v (inv==1): write to C
            #pragma unroll
            for (int fr = 0; fr < FR; ++fr)
                #pragma unroll
                for (int fc = 0; fc < 4; ++fc)
                    #pragma unroll
                    for (int r = 0; r < 4; ++r) {
                        const int row = row0 + wr * FR * 16 + fr * 16 + (l >> 4) * 4 + r;
                        const int col = col0 + wc * 64 + fc * 16 + (l & 15);
                        C[(size_t)row * Nstride + col] =
                            __float2bfloat16(acc[fr][fc][r] * inv[fc]);
                    }
        }
    } else {
        #pragma unroll
        for (int fr = 0; fr < FR; ++fr)
            #pragma unroll
            for (int fc = 0; fc < 4; ++fc)
                #pragma unroll
                for (int r = 0; r < 4; ++r) {
                    const int row = row0 + wr * FR * 16 + fr * 16 + (l >> 4) * 4 + r;
                    const int col = col0 + wc * 64 + fc * 16 + (l & 15);
                    C[(size_t)row * Nstride + col] = __float2bfloat16(acc[fr][fc][r]);
                }
    }
}

// ---------------------------------------------------------------------------
// S partials via MFMA, operands direct from global (L2-resident), k-hat
// already scaled. S_part[c][g][d1][d2] = sum_{n in chunk c} k_hat * v.
// grid (16 chunks of 256 n, 8 heads); 4 waves, wave = 16 d1 rows.
// ---------------------------------------------------------------------------
__global__ __launch_bounds__(256) void s_mfma(
    const __hip_bfloat16* __restrict__ qkv, float* __restrict__ S_part)
{
    const int c = blockIdx.x, g = blockIdx.y;
    const int tid = threadIdx.x;
    const int w = tid >> 6, l = tid & 63;
    const __hip_bfloat16* kb = qkv + (size_t)(512 + g * 64 + w * 16 + (l & 15)) * NSP;
    const __hip_bfloat16* vb = qkv + (size_t)(1024 + g * 64 + (l & 15)) * NSP;

    f32x4 acc[4];
    #pragma unroll
    for (int j = 0; j < 4; ++j) acc[j] = (f32x4){0.f, 0.f, 0.f, 0.f};

    #pragma unroll
    for (int s8 = 0; s8 < 8; ++s8) {
        const int na = c * 256 + s8 * 32 + (l >> 4) * 8;
        const bf16x8 a = *(const bf16x8*)(kb + na);
        #pragma unroll
        for (int fc = 0; fc < 4; ++fc) {
            const bf16x8 b = *(const bf16x8*)(vb + (size_t)(fc * 16) * NSP + na);
            acc[fc] = __builtin_amdgcn_mfma_f32_16x16x32_bf16(a, b, acc[fc], 0, 0, 0);
        }
    }
    float* out = S_part + (size_t)(c * 8 + g) * 4096;
    #pragma unroll
    for (int fc = 0; fc < 4; ++fc)
        #pragma unroll
        for (int r = 0; r < 4; ++r)
            out[(w * 16 + (l >> 4) * 4 + r) * 64 + fc * 16 + (l & 15)] = acc[fc][r];
}

// ---------------------------------------------------------------------------
// Reduce 16 partials; emit SbT[g][d2][d1] bf16 (B-operand layout for av).
// ---------------------------------------------------------------------------
__global__ __launch_bounds__(256) void s_reduce(
    const float* __restrict__ S_part, __hip_bfloat16* __restrict__ SbT)
{
    const int t = blockIdx.x * 256 + threadIdx.x;      // 32768
    const int g = t >> 12, rem = t & 4095;
    const int d1 = rem >> 6, d2 = rem & 63;
    float s = 0.f;
    #pragma unroll
    for (int c = 0; c < 16; ++c)
        s += S_part[(size_t)(c * 8 + g) * 4096 + d1 * 64 + d2];
    SbT[g * 4096 + d2 * 64 + d1] = __float2bfloat16(s);
}

// ---------------------------------------------------------------------------
// attnT[n][g*64+d2] = sum_d1 q_hat[n][g*64+d1] * S[g][d1][d2] (MFMA).
// q_hat is pre-scaled; S fragments register-resident.
// grid (16 n-tiles of 256, 8 heads); 4 waves, wave = 64 n rows.
// ---------------------------------------------------------------------------
__global__ __launch_bounds__(256) void av_mfma(
    const __hip_bfloat16* __restrict__ qT,
    const __hip_bfloat16* __restrict__ SbT, __hip_bfloat16* __restrict__ attnT)
{
    const int nb = blockIdx.x, g = blockIdx.y;
    const int tid = threadIdx.x;
    const int w = tid >> 6, l = tid & 63;
    const int nwave = nb * 256 + w * 64;

    bf16x8 bfr[2][4];
    #pragma unroll
    for (int ks = 0; ks < 2; ++ks)
        #pragma unroll
        for (int fc = 0; fc < 4; ++fc)
            bfr[ks][fc] = *(const bf16x8*)(
                SbT + g * 4096 + (fc * 16 + (l & 15)) * 64 + ks * 32 + (l >> 4) * 8);

    #pragma unroll
    for (int mr = 0; mr < 4; ++mr) {
        f32x4 acc[4];
        #pragma unroll
        for (int j = 0; j < 4; ++j) acc[j] = (f32x4){0.f, 0.f, 0.f, 0.f};
        #pragma unroll
        for (int ks = 0; ks < 2; ++ks) {
            const bf16x8 a = *(const bf16x8*)(
                qT + (size_t)(nwave + mr * 16 + (l & 15)) * INNER + g * 64 + ks * 32 + (l >> 4) * 8);
            #pragma unroll
            for (int fc = 0; fc < 4; ++fc)
                acc[fc] = __builtin_amdgcn_mfma_f32_16x16x32_bf16(a, bfr[ks][fc], acc[fc], 0, 0, 0);
        }
        const int nrow = nwave + mr * 16 + (l >> 4) * 4;
        #pragma unroll
        for (int fc = 0; fc < 4; ++fc)
            #pragma unroll
            for (int r = 0; r < 4; ++r)
                attnT[(size_t)(nrow + r) * INNER + g * 64 + fc * 16 + (l & 15)] =
                    __float2bfloat16(acc[fc][r]);
    }
}

// ---------------------------------------------------------------------------
// Fused BN(training stats) + ReLU, one block per channel (single pass).
// ---------------------------------------------------------------------------
__global__ __launch_bounds__(256) void bn_fused(
    const __hip_bfloat16* __restrict__ proj,
    const float* __restrict__ gamma, const float* __restrict__ beta,
    float* __restrict__ out)
{
    const int c = blockIdx.x;
    const int tid = threadIdx.x;
    const __hip_bfloat16* p = proj + (size_t)c * NSP + tid * 16;
    float v[16];
    {
        const uint4 u0 = *(const uint4*)(p);
        const uint4 u1 = *(const uint4*)(p + 8);
        const __hip_bfloat16* b0 = (const __hip_bfloat16*)&u0;
        const __hip_bfloat16* b1 = (const __hip_bfloat16*)&u1;
        #pragma unroll
        for (int j = 0; j < 8; ++j) { v[j] = __bfloat162float(b0[j]); v[8 + j] = __bfloat162float(b1[j]); }
    }
    float s = 0.f, q = 0.f;
    #pragma unroll
    for (int j = 0; j < 16; ++j) { s += v[j]; q += v[j] * v[j]; }
    #pragma unroll
    for (int m = 1; m < 64; m <<= 1) { s += __shfl_xor(s, m, 64); q += __shfl_xor(q, m, 64); }
    __shared__ float ss[4], qq[4];
    if ((tid & 63) == 0) { ss[tid >> 6] = s; qq[tid >> 6] = q; }
    __syncthreads();
    s = ss[0] + ss[1] + ss[2] + ss[3];
    q = qq[0] + qq[1] + qq[2] + qq[3];
    const float mean = s * (1.f / 4096.f);
    const float var  = q * (1.f / 4096.f) - mean * mean;
    const float scal = rsqrtf(var + 1e-5f) * gamma[c];
    const float bb   = beta[c];
    float* o = out + (size_t)c * NSP + tid * 16;
    #pragma unroll
    for (int j = 0; j < 16; j += 4) {
        float4 r;
        r.x = (v[j+0] - mean) * scal + bb; r.x = r.x > 0.f ? r.x : 0.f;
        r.y = (v[j+1] - mean) * scal + bb; r.y = r.y > 0.f ? r.y : 0.f;
        r.z = (v[j+2] - mean) * scal + bb; r.z = r.z > 0.f ? r.z : 0.f;
        r.w = (v[j+3] - mean) * scal + bb; r.w = r.w > 0.f ? r.w : 0.f;
        *(float4*)(o + j) = r;
    }
}

// ---------------------------------------------------------------------------
extern "C" void kernel_launch(void* const* d_in, const int* in_sizes, int n_in,
                              void* d_out, int out_size, void* d_ws, size_t ws_size,
                              hipStream_t stream)
{
    const float* x      = (const float*)d_in[0];   // [256, 4096]
    const float* w_qkv  = (const float*)d_in[1];   // [1536, 256]
    const float* w_out  = (const float*)d_in[2];   // [256, 512]
    const float* gamma  = (const float*)d_in[3];   // [256]
    const float* beta   = (const float*)d_in[4];   // [256]
    float* out = (float*)d_out;                    // [256, 4096]

    char* ws = (char*)d_ws;
    __hip_bfloat16* qkv_bf  = (__hip_bfloat16*)ws;                    // 12 MB (rows 512.. used: k-hat, v)
    __hip_bfloat16* xT_bf   = (__hip_bfloat16*)(ws + 12582912);       // 2 MB
    __hip_bfloat16* wqkv_bf = (__hip_bfloat16*)(ws + 14680064);       // 768 KB
    __hip_bfloat16* wout_bf = (__hip_bfloat16*)(ws + 15466496);       // 256 KB
    __hip_bfloat16* attnT   = (__hip_bfloat16*)(ws + 15728640);       // 4 MB
    __hip_bfloat16* proj_bf = (__hip_bfloat16*)(ws + 19922944);       // 2 MB
    __hip_bfloat16* qT      = (__hip_bfloat16*)(ws + 22282240);       // 4 MB
    float* S_part           = (float*)(ws + 26476544);                // 2 MB
    __hip_bfloat16* SbT     = (__hip_bfloat16*)(ws + 30670848);       // 64 KB

    // 0) input transpose + weight converts (merged)
    prep<<<512, 256, 0, stream>>>(x, w_qkv, w_out, xT_bf, wqkv_bf, wout_bf);

    // 1) qkv = w_qkv @ x (MFMA); epilogue: k-hat/v -> qkv_bf, q-hat -> qT
    gemm_bf16<CIN, 128, 4, 1><<<dim3(NSP / 128, QKV_ROWS / 128), 256, 0, stream>>>(
        wqkv_bf, xT_bf, qkv_bf, NSP, qT);

    // 2) S partials = K_hat @ V^T per head (MFMA, direct-from-global)
    s_mfma<<<dim3(16, 8), 256, 0, stream>>>(qkv_bf, S_part);

    // 3) reduce partials -> SbT bf16 [g][d2][d1]
    s_reduce<<<128, 256, 0, stream>>>(S_part, SbT);

    // 4) attnT = q_hat @ S (MFMA, S in registers)
    av_mfma<<<dim3(16, 8), 256, 0, stream>>>(qT, SbT, attnT);

    // 5) proj = w_out @ attn (MFMA, BM=64 -> 128 blocks)
    gemm_bf16<INNER, 64, 2, 0><<<dim3(NSP / 128, CIN / 64), 256, 0, stream>>>(
        wout_bf, attnT, proj_bf, NSP, nullptr);

    // 6) BN stats + normalize + ReLU (fused, per-channel)
    bn_fused<<<CIN, 256, 0, stream>>>(proj_bf, gamma, beta, out);
}